// Round 1
// baseline (668.230 us; speedup 1.0000x reference)
//
#include <hip/hip_runtime.h>
#include <hip/hip_bf16.h>

// ModulatedConv2d: B=8, CIN=32, COUT=32, K=3, H=W=512, MAPPING_DIM=1024
// style = w @ style_w^T + style_b        [8,32]
// out   = conv3x3(x * style, kernel)     [8,32,512,512]  (NCHW / OIHW, pad=1)
//
// Strategy: bf16 MFMA (16x16x32: K=CIN=32 exactly). A = weights (cout x cin),
// B = modulated x (cin x 16 pixels). Memory-bound: ~536 MB HBM floor (~85us).

typedef short  short8 __attribute__((ext_vector_type(8)));
typedef float  f32x4  __attribute__((ext_vector_type(4)));

#define TH 8
#define TW 64
#define CPAD 40   // padded cin stride in LDS (shorts): 80B -> 16B aligned b128, 2-way-conflict-free

static __device__ inline unsigned short f2bf(float f) {
    unsigned int u = __float_as_uint(f);
    unsigned int r = (u + 0x7fffu + ((u >> 16) & 1u)) >> 16;   // RNE
    return (unsigned short)r;
}

// style[b][ci] = sum_m w[b][m] * style_w[ci][m] + style_b[ci]
// one wave per (b,ci): 256 waves = 64 blocks x 256 threads
__global__ void style_kernel(const float* __restrict__ w, const float* __restrict__ sw,
                             const float* __restrict__ sb, float* __restrict__ style) {
    int wid  = (blockIdx.x * 256 + threadIdx.x) >> 6;   // 0..255
    int lane = threadIdx.x & 63;
    int b = wid >> 5, ci = wid & 31;
    const float* wp = w  + b  * 1024;
    const float* sp = sw + ci * 1024;
    float s = 0.f;
    #pragma unroll
    for (int i = 0; i < 16; ++i) s += wp[lane + 64 * i] * sp[lane + 64 * i];
    #pragma unroll
    for (int off = 32; off; off >>= 1) s += __shfl_down(s, off, 64);
    if (lane == 0) style[b * 32 + ci] = s + sb[ci];
}

// Pre-transform kernel weights to per-lane A fragments (bf16):
// wfrag[off][half][lane][j] = kernel[cout = half*16 + (lane&15)][cin = (lane>>4)*8 + j][kh][kw]
__global__ void wprep_kernel(const float* __restrict__ kern, unsigned short* __restrict__ wfrag) {
    int tid = blockIdx.x * 256 + threadIdx.x;
    if (tid >= 9 * 2 * 64 * 8) return;
    int j    = tid & 7;
    int lane = (tid >> 3) & 63;
    int half = (tid >> 9) & 1;
    int off  = tid >> 10;           // 0..8
    int cout = half * 16 + (lane & 15);
    int cin  = (lane >> 4) * 8 + j;
    int kh = off / 3, kw = off % 3;
    wfrag[tid] = f2bf(kern[(cout * 32 + cin) * 9 + kh * 3 + kw]);
}

__global__ __launch_bounds__(256) void conv_kernel(const float* __restrict__ x,
                                                   const float* __restrict__ style,
                                                   const unsigned short* __restrict__ wfrag,
                                                   float* __restrict__ out) {
    __shared__ unsigned short xs[(TH + 2) * (TW + 2) * CPAD];
    __shared__ float st[32];

    const int b  = blockIdx.z;
    const int h0 = blockIdx.y * TH;
    const int w0 = blockIdx.x * TW;
    const int t  = threadIdx.x;

    if (t < 32) st[t] = style[b * 32 + t];
    __syncthreads();

    // ---- stage x tile (with halo, zero-padded) -> LDS [row][col][cin] bf16, modulated ----
    const float* xb = x + (size_t)b * 32 * 512 * 512;
    for (int idx = t; idx < (TH + 2) * (TW + 2) * 32; idx += 256) {
        int col = idx % (TW + 2);
        int tmp = idx / (TW + 2);
        int row = tmp % (TH + 2);
        int ci  = tmp / (TH + 2);
        int gh = h0 - 1 + row, gw = w0 - 1 + col;
        float v = 0.f;
        if ((unsigned)gh < 512u && (unsigned)gw < 512u)
            v = xb[ci * 262144 + gh * 512 + gw] * st[ci];
        xs[(row * (TW + 2) + col) * CPAD + ci] = f2bf(v);
    }

    // ---- load weight fragments into registers (72 VGPRs), overlap with staging ----
    const int lane = t & 63, wave = t >> 6;
    short8 wreg[9][2];
    #pragma unroll
    for (int off = 0; off < 9; ++off)
        #pragma unroll
        for (int hf = 0; hf < 2; ++hf)
            wreg[off][hf] = *(const short8*)(wfrag + ((off * 2 + hf) * 64 + lane) * 8);

    __syncthreads();

    const int n  = lane & 15;       // pixel within 16-group (MFMA B col / C col)
    const int kg = lane >> 4;       // k-quad: cin (lane>>4)*8..+7 ; C row base kg*4
    float* ob = out + (size_t)b * 32 * 262144;

    #pragma unroll 1
    for (int g = 0; g < 8; ++g) {   // 8 groups/wave: rows {2w, 2w+1} x 4 col-groups
        const int r   = wave * 2 + (g >> 2);
        const int c16 = (g & 3) * 16;
        f32x4 acc0 = {0.f, 0.f, 0.f, 0.f};
        f32x4 acc1 = {0.f, 0.f, 0.f, 0.f};
        #pragma unroll
        for (int kh = 0; kh < 3; ++kh) {
            #pragma unroll
            for (int kw = 0; kw < 3; ++kw) {
                const short8 bfrag =
                    *(const short8*)&xs[((r + kh) * (TW + 2) + c16 + kw + n) * CPAD + kg * 8];
                const int off = kh * 3 + kw;
                acc0 = __builtin_amdgcn_mfma_f32_16x16x32_bf16(wreg[off][0], bfrag, acc0, 0, 0, 0);
                acc1 = __builtin_amdgcn_mfma_f32_16x16x32_bf16(wreg[off][1], bfrag, acc1, 0, 0, 0);
            }
        }
        // C/D layout: col = lane&15 = pixel, row = kg*4 + reg = cout (within half)
        const int gh = h0 + r, gw = w0 + c16 + n;
        #pragma unroll
        for (int reg = 0; reg < 4; ++reg) {
            const int co = kg * 4 + reg;
            ob[(size_t)co * 262144 + gh * 512 + gw]        = acc0[reg];
            ob[(size_t)(co + 16) * 262144 + gh * 512 + gw] = acc1[reg];
        }
    }
}

extern "C" void kernel_launch(void* const* d_in, const int* in_sizes, int n_in,
                              void* d_out, int out_size, void* d_ws, size_t ws_size,
                              hipStream_t stream) {
    const float* x    = (const float*)d_in[0];   // [8,32,512,512]
    const float* w    = (const float*)d_in[1];   // [8,1024]
    const float* kern = (const float*)d_in[2];   // [32,32,3,3]
    const float* sw   = (const float*)d_in[3];   // [32,1024]
    const float* sb   = (const float*)d_in[4];   // [32]
    float* out = (float*)d_out;                  // [8,32,512,512] fp32

    float*          style = (float*)d_ws;                               // 256 floats
    unsigned short* wfrag = (unsigned short*)((char*)d_ws + 1024);      // 9216 bf16

    style_kernel<<<64, 256, 0, stream>>>(w, sw, sb, style);
    wprep_kernel<<<36, 256, 0, stream>>>(kern, wfrag);
    conv_kernel<<<dim3(512 / TW, 512 / TH, 8), 256, 0, stream>>>(x, style, wfrag, out);
}

// Round 2
// 507.673 us; speedup vs baseline: 1.3163x; 1.3163x over previous
//
#include <hip/hip_runtime.h>
#include <hip/hip_bf16.h>

// ModulatedConv2d: B=8, CIN=32, COUT=32, K=3, H=W=512, MAPPING_DIM=1024
// style = w @ style_w^T + style_b    [8,32]
// out   = conv3x3(x, kernel * style[b,cin])   (style folded into weights)
//
// bf16 MFMA 16x16x32 (K=CIN=32 exactly). Roles: A = x pixels (m=16 pixels),
// B = modulated weights (n=16 couts). C/D: col=lane&15=cout, row=kg*4+reg =
// 4 CONSECUTIVE pixels per lane -> dwordx4 epilogue stores.
// Memory floor ~536 MB -> ~85us; R1 was issue-rate bound (scalar ld/st).

typedef short  short8 __attribute__((ext_vector_type(8)));
typedef float  f32x4  __attribute__((ext_vector_type(4)));

#define TH 8
#define TW 32
#define XCOLS (TH ? (TW + 2) : 0)   // 34 staged cols (output cols -1 .. TW)
#define CPAD 40   // cin stride in LDS shorts: 80 B -> 16B-aligned b128, 2-way-conflict-free

static __device__ inline unsigned short f2bf(float f) {
    unsigned int u = __float_as_uint(f);
    unsigned int r = (u + 0x7fffu + ((u >> 16) & 1u)) >> 16;   // RNE
    return (unsigned short)r;
}

// style[b][ci] = sum_m w[b][m] * style_w[ci][m] + style_b[ci]; one wave per (b,ci)
__global__ void style_kernel(const float* __restrict__ w, const float* __restrict__ sw,
                             const float* __restrict__ sb, float* __restrict__ style) {
    int wid  = (blockIdx.x * 256 + threadIdx.x) >> 6;   // 0..255
    int lane = threadIdx.x & 63;
    int b = wid >> 5, ci = wid & 31;
    const float* wp = w  + b  * 1024;
    const float* sp = sw + ci * 1024;
    float s = 0.f;
    #pragma unroll
    for (int i = 0; i < 16; ++i) s += wp[lane + 64 * i] * sp[lane + 64 * i];
    #pragma unroll
    for (int off = 32; off; off >>= 1) s += __shfl_down(s, off, 64);
    if (lane == 0) style[b * 32 + ci] = s + sb[ci];
}

// Per-sample modulated weight fragments, MFMA B-operand layout:
// wfrag[b][off][half][lane][j] = kern[cout=half*16+(lane&15)][cin=(lane>>4)*8+j][kh][kw]
//                               * style[b][cin]
__global__ void wprep_kernel(const float* __restrict__ kern, const float* __restrict__ style,
                             unsigned short* __restrict__ wfrag) {
    int tid = blockIdx.x * 256 + threadIdx.x;
    if (tid >= 8 * 9216) return;
    int b    = tid / 9216;
    int rem  = tid % 9216;
    int off  = rem >> 10;            // 0..8
    int r2   = rem & 1023;
    int half = r2 >> 9;
    int lane = (r2 >> 3) & 63;
    int j    = r2 & 7;
    int cout = half * 16 + (lane & 15);
    int cin  = (lane >> 4) * 8 + j;
    int kh = off / 3, kw = off % 3;
    float v = kern[(cout * 32 + cin) * 9 + kh * 3 + kw] * style[b * 32 + cin];
    wfrag[tid] = f2bf(v);
}

__global__ __launch_bounds__(256, 4) void conv_kernel(const float* __restrict__ x,
                                                      const unsigned short* __restrict__ wfrag,
                                                      float* __restrict__ out) {
    __shared__ unsigned short xs[(TH + 2) * XCOLS * CPAD];   // 10*34*40*2 = 27200 B

    const int b  = blockIdx.z;
    const int h0 = blockIdx.y * TH;
    const int w0 = blockIdx.x * TW;
    const int t    = threadIdx.x;
    const int lane = t & 63, wave = t >> 6;

    // ---- weight fragments -> 72 VGPRs (independent of LDS staging) ----
    short8 wreg[9][2];
    const unsigned short* wf = wfrag + b * 9216;
    #pragma unroll
    for (int off = 0; off < 9; ++off)
        #pragma unroll
        for (int hf = 0; hf < 2; ++hf)
            wreg[off][hf] = *(const short8*)(wf + ((off * 2 + hf) * 64 + lane) * 8);

    // ---- stage x tile -> LDS [row][col][cin] bf16; float4 loads, b32 writes ----
    // 10 rows x 10 float4-cols (gw w0-4 .. w0+35) x 16 cin-pairs = 1600 tasks
    const float* xb = x + (size_t)b * 8388608;
    for (int tt = t; tt < 1600; tt += 256) {
        int col4 = tt % 10;
        int tmp  = tt / 10;
        int row  = tmp % 10;
        int cp   = tmp / 10;                 // cin pair 0..15
        int gh   = h0 - 1 + row;
        int gw0  = w0 - 4 + col4 * 4;
        f32x4 a = {0.f, 0.f, 0.f, 0.f};
        f32x4 c = {0.f, 0.f, 0.f, 0.f};
        if ((unsigned)gh < 512u && (unsigned)gw0 <= 508u) {
            const float* p = xb + cp * 2 * 262144 + gh * 512 + gw0;
            a = *(const f32x4*)p;
            c = *(const f32x4*)(p + 262144);
        }
        #pragma unroll
        for (int e = 0; e < 4; ++e) {
            int xcol = col4 * 4 + e - 3;     // -3..36, keep 0..33
            if ((unsigned)xcol < (unsigned)XCOLS) {
                float2 fp = make_float2(a[e], c[e]);
                __hip_bfloat162 h2 = __float22bfloat162_rn(fp);
                *(unsigned int*)&xs[(row * XCOLS + xcol) * CPAD + cp * 2] = *(unsigned int*)&h2;
            }
        }
    }
    __syncthreads();

    const int n  = lane & 15;    // A-operand m = pixel within 16-group; C col = cout
    const int kg = lane >> 4;    // k-quad: cin kg*8..+7; C rows kg*4..+3 = pixels
    float* ob = out + (size_t)b * 8388608;

    #pragma unroll 1
    for (int g = 0; g < 4; ++g) {            // wave: rows {2w,2w+1} x 2 col16-groups
        const int r   = wave * 2 + (g >> 1);
        const int c16 = (g & 1) * 16;
        f32x4 acc0 = {0.f, 0.f, 0.f, 0.f};
        f32x4 acc1 = {0.f, 0.f, 0.f, 0.f};
        #pragma unroll
        for (int kh = 0; kh < 3; ++kh) {
            #pragma unroll
            for (int kw = 0; kw < 3; ++kw) {
                const short8 afrag =
                    *(const short8*)&xs[((r + kh) * XCOLS + c16 + kw + n) * CPAD + kg * 8];
                const int off = kh * 3 + kw;
                acc0 = __builtin_amdgcn_mfma_f32_16x16x32_bf16(afrag, wreg[off][0], acc0, 0, 0, 0);
                acc1 = __builtin_amdgcn_mfma_f32_16x16x32_bf16(afrag, wreg[off][1], acc1, 0, 0, 0);
            }
        }
        // C/D: col = lane&15 = cout (within half), rows kg*4+reg = 4 consecutive pixels
        const int gh = h0 + r;
        const int gw = w0 + c16 + kg * 4;
        float* p0 = ob + (size_t)n * 262144 + gh * 512 + gw;
        *(f32x4*)p0 = acc0;
        *(f32x4*)(p0 + 16 * 262144) = acc1;
    }
}

extern "C" void kernel_launch(void* const* d_in, const int* in_sizes, int n_in,
                              void* d_out, int out_size, void* d_ws, size_t ws_size,
                              hipStream_t stream) {
    const float* x    = (const float*)d_in[0];   // [8,32,512,512]
    const float* w    = (const float*)d_in[1];   // [8,1024]
    const float* kern = (const float*)d_in[2];   // [32,32,3,3]
    const float* sw   = (const float*)d_in[3];   // [32,1024]
    const float* sb   = (const float*)d_in[4];   // [32]
    float* out = (float*)d_out;                  // [8,32,512,512] fp32

    float*          style = (float*)d_ws;                           // 256 floats
    unsigned short* wfrag = (unsigned short*)((char*)d_ws + 1024);  // 8*9216 bf16

    style_kernel<<<64, 256, 0, stream>>>(w, sw, sb, style);
    wprep_kernel<<<288, 256, 0, stream>>>(kern, style, wfrag);
    conv_kernel<<<dim3(512 / TW, 512 / TH, 8), 256, 0, stream>>>(x, wfrag, out);
}